// Round 2
// baseline (1234.102 us; speedup 1.0000x reference)
//
#include <hip/hip_runtime.h>
#include <hip/hip_bf16.h>
#include <stdint.h>

#define C_DIM 768
#define HW 16384
#define EPSF 1e-8f

typedef __attribute__((ext_vector_type(8))) __bf16 bf16x8;
typedef __attribute__((ext_vector_type(4))) float floatx4;

// ---------------- Kernel A: per-channel means over spatial dim ----------------
__global__ __launch_bounds__(256) void k_means(const float* __restrict__ x,
                                               const float* __restrict__ s,
                                               float* __restrict__ meanA,
                                               float* __restrict__ meanB) {
  int ch = blockIdx.x;
  const float* src = (ch < C_DIM) ? (x + (size_t)ch * HW) : (s + (size_t)(ch - C_DIM) * HW);
  int t = threadIdx.x;
  float acc = 0.f;
  for (int i = t; i < HW; i += 256) acc += src[i];
  __shared__ float red[256];
  red[t] = acc;
  __syncthreads();
  for (int o = 128; o > 0; o >>= 1) {
    if (t < o) red[t] += red[t + o];
    __syncthreads();
  }
  if (t == 0) {
    float m = red[0] * (1.0f / HW);
    if (ch < C_DIM) meanA[ch] = m; else meanB[ch - C_DIM] = m;
  }
}

// ---------------- Kernel B: norms + centered bf16 transpose ----------------
__global__ __launch_bounds__(256) void k_prep(const float* __restrict__ x,
                                              const float* __restrict__ s,
                                              const float* __restrict__ meanA,
                                              const float* __restrict__ meanB,
                                              __hip_bfloat16* __restrict__ Abf,
                                              __hip_bfloat16* __restrict__ Bbf,
                                              float* __restrict__ invbn,
                                              float* __restrict__ rawNA,
                                              float* __restrict__ rawNB) {
  __shared__ float la[64 * 33];   // [col][r], stride 33 kills bank conflicts
  __shared__ float lb[64 * 33];
  __shared__ float lma[C_DIM];
  __shared__ float lmb[C_DIM];
  __shared__ float red[3 * 256];
  int t = threadIdx.x;
  int j0 = blockIdx.x * 64;
  for (int c = t; c < C_DIM; c += 256) { lma[c] = meanA[c]; lmb[c] = meanB[c]; }

  int col = t & 63;  // position within tile (for reduction)
  int rr = t >> 6;   // 0..3
  float ssa = 0.f, ssb = 0.f, cssb = 0.f;

  for (int c0 = 0; c0 < C_DIM; c0 += 32) {
    __syncthreads();  // protect LDS tiles (also covers the mean preload on iter 0)
#pragma unroll
    for (int sIt = 0; sIt < 8; ++sIt) {
      int idx = t + sIt * 256;
      int r = idx >> 6, cc = idx & 63;
      la[cc * 33 + r] = x[(size_t)(c0 + r) * HW + j0 + cc];
      lb[cc * 33 + r] = s[(size_t)(c0 + r) * HW + j0 + cc];
    }
    __syncthreads();
#pragma unroll
    for (int q = 0; q < 8; ++q) {
      int r = rr * 8 + q;
      float av = la[col * 33 + r];
      float bv = lb[col * 33 + r];
      ssa += av * av;
      ssb += bv * bv;
      float bc = bv - lmb[c0 + r];
      cssb += bc * bc;
    }
    // transposed bf16 writes: [j][c] layout, K contiguous
#pragma unroll
    for (int sIt = 0; sIt < 8; ++sIt) {
      int idx = t + sIt * 256;
      int j = idx >> 5, k = idx & 31;
      float av = la[j * 33 + k] - lma[c0 + k];
      float bv = lb[j * 33 + k] - lmb[c0 + k];
      Abf[(size_t)(j0 + j) * C_DIM + c0 + k] = __float2bfloat16(av);
      Bbf[(size_t)(j0 + j) * C_DIM + c0 + k] = __float2bfloat16(bv);
    }
  }
  red[t] = ssa; red[256 + t] = ssb; red[512 + t] = cssb;
  __syncthreads();
  if (t < 64) {
    float sa = red[t] + red[t + 64] + red[t + 128] + red[t + 192];
    float sb = red[256 + t] + red[256 + t + 64] + red[256 + t + 128] + red[256 + t + 192];
    float sc = red[512 + t] + red[512 + t + 64] + red[512 + t + 128] + red[512 + t + 192];
    rawNA[j0 + t] = sqrtf(sa);
    rawNB[j0 + t] = sqrtf(sb);
    invbn[j0 + t] = 1.0f / (sqrtf(sc + EPSF) + EPSF);
  }
}

// ---------------- Kernel C: MFMA GEMM with fused argmax epilogue ----------------
// BK=64, XOR-swizzled LDS chunk placement:
//  - storage slot for (row, chunk c) is (row*8 + (c ^ (row&7)))*16B  [chunk = 16B = 8 bf16]
//  - global_load_lds writes are lane-linear (slot = sIt*256 + t), so the swizzle is
//    expressed by permuting WHICH global chunk each thread fetches.
//  - fragment ds_read_b128: lanes 0..7 hit 8 distinct bank groups (conflict-free;
//    16-lane aliasing is 2-way = free).
__device__ __forceinline__ void gl_lds16(const void* g, void* l) {
  __builtin_amdgcn_global_load_lds((const __attribute__((address_space(1))) uint32_t*)g,
                                   (__attribute__((address_space(3))) uint32_t*)l, 16, 0, 0);
}

__global__ __launch_bounds__(256) void k_gemm_argmax(
    const __hip_bfloat16* __restrict__ Abf,
    const __hip_bfloat16* __restrict__ Bbf,
    const float* __restrict__ invbn,
    unsigned long long* __restrict__ best) {
  __shared__ alignas(16) __hip_bfloat16 As[128 * 64];   // 16 KB
  __shared__ alignas(16) __hip_bfloat16 Bs[128 * 64];   // 16 KB
  int t = threadIdx.x;
  int bx = blockIdx.x & 127;
  int by = blockIdx.x >> 7;
  int i0 = by * 128, j0 = bx * 128;
  int lane = t & 63, w = t >> 6;
  int wm = w >> 1, wn = w & 1;

  floatx4 acc[4][4];
#pragma unroll
  for (int a1 = 0; a1 < 4; ++a1)
#pragma unroll
    for (int a2 = 0; a2 < 4; ++a2) acc[a1][a2] = (floatx4){0.f, 0.f, 0.f, 0.f};

  // staging: thread t -> row t>>3 (+32 per sIt), chunk c = (t&7) ^ ((t>>3)&7)
  int srowT = t >> 3;                      // 0..31
  int cS = (t & 7) ^ ((t >> 3) & 7);       // swizzled source chunk (sIt-invariant)
  const __hip_bfloat16* aSrc = Abf + (size_t)(i0 + srowT) * C_DIM + cS * 8;
  const __hip_bfloat16* bSrc = Bbf + (size_t)(j0 + srowT) * C_DIM + cS * 8;
  __hip_bfloat16* aDst = &As[t * 8];
  __hip_bfloat16* bDst = &Bs[t * 8];
  const size_t rowSkip = (size_t)32 * C_DIM;

  int mrow = lane & 15;
  int q = lane >> 4;      // 0..3
  int sw = mrow & 7;      // read-side swizzle key

  for (int k0 = 0; k0 < C_DIM; k0 += 64) {
    __syncthreads();
#pragma unroll
    for (int sIt = 0; sIt < 4; ++sIt) {
      gl_lds16(aSrc + k0 + sIt * rowSkip, aDst + sIt * 2048);
      gl_lds16(bSrc + k0 + sIt * rowSkip, bDst + sIt * 2048);
    }
    __syncthreads();
#pragma unroll
    for (int kh = 0; kh < 2; ++kh) {
      int kqe = ((kh * 4 + q) ^ sw) * 8;   // swizzled element offset within row
      bf16x8 af[4], bfr[4];
#pragma unroll
      for (int tm = 0; tm < 4; ++tm)
        af[tm] = *(const bf16x8*)&As[(wm * 64 + tm * 16 + mrow) * 64 + kqe];
#pragma unroll
      for (int tn = 0; tn < 4; ++tn)
        bfr[tn] = *(const bf16x8*)&Bs[(wn * 64 + tn * 16 + mrow) * 64 + kqe];
#pragma unroll
      for (int tm = 0; tm < 4; ++tm)
#pragma unroll
        for (int tn = 0; tn < 4; ++tn)
          acc[tm][tn] = __builtin_amdgcn_mfma_f32_16x16x32_bf16(af[tm], bfr[tn], acc[tm][tn], 0, 0, 0);
    }
  }

  // epilogue: apply per-column 1/bn_j, per-row argmax, packed atomicMax
  int colid = lane & 15;
  int quad = lane >> 4;
  float ib[4];
#pragma unroll
  for (int tn = 0; tn < 4; ++tn) ib[tn] = invbn[j0 + wn * 64 + tn * 16 + colid];

#pragma unroll
  for (int tm = 0; tm < 4; ++tm) {
#pragma unroll
    for (int r = 0; r < 4; ++r) {
      int i = i0 + wm * 64 + tm * 16 + quad * 4 + r;
      float bestv = -3.0e38f;
      int bestj = 0x7FFFFFFF;
#pragma unroll
      for (int tn = 0; tn < 4; ++tn) {
        int j = j0 + wn * 64 + tn * 16 + colid;
        float v = acc[tm][tn][r] * ib[tn];
        if (v > bestv) { bestv = v; bestj = j; }   // strict >: lowest j wins ties
      }
#pragma unroll
      for (int off = 1; off < 16; off <<= 1) {
        float ov = __shfl_xor(bestv, off, 64);
        int oj = __shfl_xor(bestj, off, 64);
        if (ov > bestv || (ov == bestv && oj < bestj)) { bestv = ov; bestj = oj; }
      }
      if (colid == 0) {
        unsigned key = __float_as_uint(bestv);
        key = (key & 0x80000000u) ? ~key : (key | 0x80000000u);
        unsigned long long packed =
            ((unsigned long long)key << 32) | (unsigned long long)(0xFFFFFFFFu - (unsigned)bestj);
        atomicMax(&best[i], packed);
      }
    }
  }
}

// ---------------- Kernel D: final cosine loss on raw columns ----------------
__global__ __launch_bounds__(256) void k_loss(const float* __restrict__ x,
                                              const float* __restrict__ s,
                                              const unsigned long long* __restrict__ best,
                                              const float* __restrict__ rawNA,
                                              const float* __restrict__ rawNB,
                                              float* __restrict__ out) {
  int i = blockIdx.x * 256 + threadIdx.x;
  unsigned j = 0xFFFFFFFFu - (unsigned)(best[i] & 0xFFFFFFFFull);
  float dot = 0.f;
  for (int c = 0; c < C_DIM; ++c)
    dot += x[(size_t)c * HW + i] * s[(size_t)c * HW + j];
  float cs = dot / ((rawNA[i] + EPSF) * (rawNB[j] + EPSF));
  float term = (1.0f - cs) * (1.0f / HW);
  __shared__ float red[256];
  int t = threadIdx.x;
  red[t] = term;
  __syncthreads();
  for (int o = 128; o > 0; o >>= 1) {
    if (t < o) red[t] += red[t + o];
    __syncthreads();
  }
  if (t == 0) atomicAdd(out, red[0]);
}

// ---------------- Launch ----------------
extern "C" void kernel_launch(void* const* d_in, const int* in_sizes, int n_in,
                              void* d_out, int out_size, void* d_ws, size_t ws_size,
                              hipStream_t stream) {
  const float* x = (const float*)d_in[0];
  const float* s = (const float*)d_in[1];
  char* ws = (char*)d_ws;
  float* meanA = (float*)(ws + 0);
  float* meanB = (float*)(ws + 4096);
  float* invbn = (float*)(ws + 8192);
  float* rawNA = (float*)(ws + 73728);
  float* rawNB = (float*)(ws + 139264);
  unsigned long long* best = (unsigned long long*)(ws + 204800);
  __hip_bfloat16* Abf = (__hip_bfloat16*)(ws + 524288);
  __hip_bfloat16* Bbf = (__hip_bfloat16*)(ws + 524288 + 25165824);
  float* out = (float*)d_out;

  hipMemsetAsync(best, 0, HW * sizeof(unsigned long long), stream);
  hipMemsetAsync(out, 0, sizeof(float), stream);
  k_means<<<2 * C_DIM, 256, 0, stream>>>(x, s, meanA, meanB);
  k_prep<<<HW / 64, 256, 0, stream>>>(x, s, meanA, meanB, Abf, Bbf, invbn, rawNA, rawNB);
  k_gemm_argmax<<<(HW / 128) * (HW / 128), 256, 0, stream>>>(Abf, Bbf, invbn, best);
  k_loss<<<HW / 256, 256, 0, stream>>>(x, s, best, rawNA, rawNB, out);
}

// Round 3
// 988.926 us; speedup vs baseline: 1.2479x; 1.2479x over previous
//
#include <hip/hip_runtime.h>
#include <hip/hip_bf16.h>
#include <stdint.h>

#define C_DIM 768
#define HW 16384
#define EPSF 1e-8f
#define JCH 32                 // B rows per streamed chunk
#define NCH (HW / JCH)         // 512 chunks
#define CPR 96                 // 16B chunks per 768-col row
#define STG 12                 // global_load_lds instrs per thread per 32-row stage

typedef __attribute__((ext_vector_type(8))) __bf16 bf16x8;
typedef __attribute__((ext_vector_type(4))) float floatx4;

// ---------------- Kernel A: per-channel means over spatial dim ----------------
__global__ __launch_bounds__(256) void k_means(const float* __restrict__ x,
                                               const float* __restrict__ s,
                                               float* __restrict__ meanA,
                                               float* __restrict__ meanB) {
  int ch = blockIdx.x;
  const float* src = (ch < C_DIM) ? (x + (size_t)ch * HW) : (s + (size_t)(ch - C_DIM) * HW);
  int t = threadIdx.x;
  float acc = 0.f;
  for (int i = t; i < HW; i += 256) acc += src[i];
  __shared__ float red[256];
  red[t] = acc;
  __syncthreads();
  for (int o = 128; o > 0; o >>= 1) {
    if (t < o) red[t] += red[t + o];
    __syncthreads();
  }
  if (t == 0) {
    float m = red[0] * (1.0f / HW);
    if (ch < C_DIM) meanA[ch] = m; else meanB[ch - C_DIM] = m;
  }
}

// ---------------- Kernel B: norms + centered bf16 transpose ----------------
__global__ __launch_bounds__(256) void k_prep(const float* __restrict__ x,
                                              const float* __restrict__ s,
                                              const float* __restrict__ meanA,
                                              const float* __restrict__ meanB,
                                              __hip_bfloat16* __restrict__ Abf,
                                              __hip_bfloat16* __restrict__ Bbf,
                                              float* __restrict__ invbn,
                                              float* __restrict__ rawNA,
                                              float* __restrict__ rawNB) {
  __shared__ float la[64 * 33];   // [col][r], stride 33 kills bank conflicts
  __shared__ float lb[64 * 33];
  __shared__ float lma[C_DIM];
  __shared__ float lmb[C_DIM];
  __shared__ float red[3 * 256];
  int t = threadIdx.x;
  int j0 = blockIdx.x * 64;
  for (int c = t; c < C_DIM; c += 256) { lma[c] = meanA[c]; lmb[c] = meanB[c]; }

  int col = t & 63;  // position within tile (for reduction)
  int rr = t >> 6;   // 0..3
  float ssa = 0.f, ssb = 0.f, cssb = 0.f;

  int wj = t >> 2;            // write phase: j 0..63
  int wk = (t & 3) * 8;       // k8 in {0,8,16,24}

  for (int c0 = 0; c0 < C_DIM; c0 += 32) {
    __syncthreads();
#pragma unroll
    for (int sIt = 0; sIt < 8; ++sIt) {
      int idx = t + sIt * 256;
      int r = idx >> 6, cc = idx & 63;
      la[cc * 33 + r] = x[(size_t)(c0 + r) * HW + j0 + cc];
      lb[cc * 33 + r] = s[(size_t)(c0 + r) * HW + j0 + cc];
    }
    __syncthreads();
#pragma unroll
    for (int q = 0; q < 8; ++q) {
      int r = rr * 8 + q;
      float av = la[col * 33 + r];
      float bv = lb[col * 33 + r];
      ssa += av * av;
      ssb += bv * bv;
      float bc = bv - lmb[c0 + r];
      cssb += bc * bc;
    }
    // transposed bf16 writes, vectorized: one bf16x8 per thread for A and B
    {
      bf16x8 pa, pb;
#pragma unroll
      for (int u = 0; u < 8; ++u) {
        pa[u] = (__bf16)(la[wj * 33 + wk + u] - lma[c0 + wk + u]);
        pb[u] = (__bf16)(lb[wj * 33 + wk + u] - lmb[c0 + wk + u]);
      }
      *(bf16x8*)&Abf[(size_t)(j0 + wj) * C_DIM + c0 + wk] = pa;
      *(bf16x8*)&Bbf[(size_t)(j0 + wj) * C_DIM + c0 + wk] = pb;
    }
  }
  red[t] = ssa; red[256 + t] = ssb; red[512 + t] = cssb;
  __syncthreads();
  if (t < 64) {
    float sa = red[t] + red[t + 64] + red[t + 128] + red[t + 192];
    float sb = red[256 + t] + red[256 + t + 64] + red[256 + t + 128] + red[256 + t + 192];
    float sc = red[512 + t] + red[512 + t + 64] + red[512 + t + 128] + red[512 + t + 192];
    rawNA[j0 + t] = sqrtf(sa);
    rawNB[j0 + t] = sqrtf(sb);
    invbn[j0 + t] = 1.0f / (sqrtf(sc + EPSF) + EPSF);
  }
}

// ---------------- Kernel B2: fold invbn into Bbf (so GEMM loop has no VGPR loads) ----
__device__ __forceinline__ unsigned short f2bf(float f) {
  __hip_bfloat16 h = __float2bfloat16(f);
  return *(unsigned short*)&h;
}

__global__ __launch_bounds__(256) void k_scaleb(__hip_bfloat16* __restrict__ B,
                                                const float* __restrict__ invbn) {
  int idx = blockIdx.x * 256 + threadIdx.x;      // one 16B chunk per thread
  int j = idx / CPR;
  float sc = invbn[j];
  uint4* p = (uint4*)B + idx;
  uint4 v = *p;
  unsigned* u = (unsigned*)&v;
#pragma unroll
  for (int q = 0; q < 4; ++q) {
    float lo = __uint_as_float((u[q] & 0xffffu) << 16) * sc;
    float hi = __uint_as_float(u[q] & 0xffff0000u) * sc;
    u[q] = (unsigned)f2bf(lo) | ((unsigned)f2bf(hi) << 16);
  }
  *p = v;
}

// ---------------- Kernel C: B-streaming GEMM + fused per-row argmax ----------------
// Block b owns rows [64b, 64b+64). A held in registers (96 VGPR/lane for K=768).
// B streamed in 32-row chunks through a 3-buffer LDS ring with fine-grained
// s_waitcnt vmcnt(N) + raw s_barrier (AITER-style pipeline).
// LDS chunk layout: slot (row j, chunk c) stored at c' = (c&~7)|((c^j)&7) — write
// side is lane-linear global_load_lds (swizzle applied to WHICH global chunk a lane
// fetches); read side b128 is conflict-free (verified-zero in R2 with same pattern).
__device__ __forceinline__ void gl_lds16(const void* g, void* l) {
  __builtin_amdgcn_global_load_lds((const __attribute__((address_space(1))) uint32_t*)g,
                                   (__attribute__((address_space(3))) uint32_t*)l, 16, 0, 0);
}

__global__ __launch_bounds__(256, 1) void k_gemm_argmax(
    const __hip_bfloat16* __restrict__ Abf,
    const __hip_bfloat16* __restrict__ Bbf,
    int* __restrict__ best) {
  __shared__ alignas(16) __hip_bfloat16 Bs[3][JCH * C_DIM];   // 3 x 48 KB
  int t = threadIdx.x;
  int lane = t & 63, w = t >> 6;
  int i0 = blockIdx.x * 64;
  int m = lane & 15, q = lane >> 4;

  // precomputed per-thread stage offsets (chunk-invariant)
  int soff[STG];
#pragma unroll
  for (int it = 0; it < STG; ++it) {
    int sl = it * 256 + t;
    int j = sl / CPR, cs = sl - j * CPR;
    int c = (cs & ~7) | ((cs ^ j) & 7);
    soff[it] = j * C_DIM + c * 8;
  }

#define STAGE(srcbase, bufid)                                              \
  {                                                                        \
    const __hip_bfloat16* _s = (srcbase);                                  \
    __hip_bfloat16* _d = &Bs[bufid][0] + t * 8;                            \
    _Pragma("unroll")                                                      \
    for (int it = 0; it < STG; ++it)                                       \
      gl_lds16(_s + soff[it], _d + it * 2048);                             \
  }

  // --- stage A tile (64 rows) into ring bufs 0,1; pull fragments to registers ---
  STAGE(Abf + (size_t)i0 * C_DIM, 0);
  STAGE(Abf + (size_t)(i0 + 32) * C_DIM, 1);
  asm volatile("s_waitcnt vmcnt(0)" ::: "memory");
  __builtin_amdgcn_s_barrier();

  bf16x8 a_res[24];
  {
    const __hip_bfloat16* abuf = &Bs[w >> 1][0];
    int rb = (w & 1) * 16 + m;          // row within the 32-row buffer
    int rbase = rb * C_DIM;
#pragma unroll
    for (int k = 0; k < 24; ++k) {
      int c = k * 4 + q;
      int cp = (c & ~7) | ((c ^ rb) & 7);
      a_res[k] = *(const bf16x8*)&abuf[rbase + cp * 8];
    }
  }
  asm volatile("s_waitcnt lgkmcnt(0)" ::: "memory");
  __builtin_amdgcn_s_barrier();

  // --- prefetch B chunks 0,1,2 ---
  STAGE(Bbf, 0);
  STAGE(Bbf + (size_t)JCH * C_DIM, 1);
  STAGE(Bbf + (size_t)(2 * JCH) * C_DIM, 2);

  float bestv[4];
  int bestj[4];
#pragma unroll
  for (int r = 0; r < 4; ++r) { bestv[r] = -3.0e38f; bestj[r] = 0; }

  int rb0 = m * C_DIM;            // jn=0 row base (jn*16 ≡ 0 mod 8 → same swizzle)
  int rb1 = (16 + m) * C_DIM;

  for (int ch = 0; ch < NCH; ++ch) {
    // wait until chunk ch's stage (oldest outstanding) has landed, then barrier
    if (ch < NCH - 2)      asm volatile("s_waitcnt vmcnt(24)" ::: "memory");
    else if (ch == NCH - 2) asm volatile("s_waitcnt vmcnt(12)" ::: "memory");
    else                    asm volatile("s_waitcnt vmcnt(0)" ::: "memory");
    __builtin_amdgcn_s_barrier();

    const __hip_bfloat16* buf = &Bs[ch % 3][0];
    floatx4 acc[2][2];
    acc[0][0] = (floatx4){0.f, 0.f, 0.f, 0.f};
    acc[0][1] = (floatx4){0.f, 0.f, 0.f, 0.f};
    acc[1][0] = (floatx4){0.f, 0.f, 0.f, 0.f};
    acc[1][1] = (floatx4){0.f, 0.f, 0.f, 0.f};
#pragma unroll
    for (int k = 0; k < 24; ++k) {
      int c = k * 4 + q;
      int cp8 = ((c & ~7) | ((c ^ m) & 7)) * 8;
      bf16x8 b0 = *(const bf16x8*)&buf[rb0 + cp8];
      bf16x8 b1 = *(const bf16x8*)&buf[rb1 + cp8];
      acc[0][k & 1] = __builtin_amdgcn_mfma_f32_16x16x32_bf16(a_res[k], b0, acc[0][k & 1], 0, 0, 0);
      acc[1][k & 1] = __builtin_amdgcn_mfma_f32_16x16x32_bf16(a_res[k], b1, acc[1][k & 1], 0, 0, 0);
    }
    // per-lane running argmax (j ascending: jn=0 then jn=1; strict > keeps lowest j)
    int jb = ch * JCH + m;
#pragma unroll
    for (int jn = 0; jn < 2; ++jn) {
      floatx4 v = acc[jn][0] + acc[jn][1];
      int j = jb + jn * 16;
#pragma unroll
      for (int r = 0; r < 4; ++r) {
        if (v[r] > bestv[r]) { bestv[r] = v[r]; bestj[r] = j; }
      }
    }
    __builtin_amdgcn_s_barrier();   // all waves done reading buf[ch%3]
    int nx = ch + 3;
    if (nx < NCH) STAGE(Bbf + (size_t)nx * JCH * C_DIM, nx % 3);
  }

  // final cross-lane reduce (16 lanes share row q*4+r), no atomics: rows owned
#pragma unroll
  for (int r = 0; r < 4; ++r) {
    float bv = bestv[r]; int bj = bestj[r];
#pragma unroll
    for (int off = 1; off < 16; off <<= 1) {
      float ov = __shfl_xor(bv, off, 64);
      int oj = __shfl_xor(bj, off, 64);
      if (ov > bv || (ov == bv && oj < bj)) { bv = ov; bj = oj; }
    }
    if (m == 0) best[i0 + w * 16 + q * 4 + r] = bj;
  }
#undef STAGE
}

// ---------------- Kernel D1: partial dots (c split 4 ways for parallelism) ------
__global__ __launch_bounds__(256) void k_loss1(const float* __restrict__ x,
                                               const float* __restrict__ s,
                                               const int* __restrict__ best,
                                               float* __restrict__ dotbuf) {
  int bid = blockIdx.x;
  int ib = bid & 63, seg = bid >> 6;
  int i = ib * 256 + threadIdx.x;
  int j = best[i];
  int c0 = seg * 192;
  float dot = 0.f;
  for (int c = c0; c < c0 + 192; ++c)
    dot += x[(size_t)c * HW + i] * s[(size_t)c * HW + j];
  atomicAdd(&dotbuf[i], dot);
}

// ---------------- Kernel D2: final cosine loss ----------------
__global__ __launch_bounds__(256) void k_loss2(const float* __restrict__ dotbuf,
                                               const int* __restrict__ best,
                                               const float* __restrict__ rawNA,
                                               const float* __restrict__ rawNB,
                                               float* __restrict__ out) {
  int i = blockIdx.x * 256 + threadIdx.x;
  int j = best[i];
  float cs = dotbuf[i] / ((rawNA[i] + EPSF) * (rawNB[j] + EPSF));
  float term = (1.0f - cs) * (1.0f / HW);
  __shared__ float red[256];
  int t = threadIdx.x;
  red[t] = term;
  __syncthreads();
  for (int o = 128; o > 0; o >>= 1) {
    if (t < o) red[t] += red[t + o];
    __syncthreads();
  }
  if (t == 0) atomicAdd(out, red[0]);
}

// ---------------- Launch ----------------
extern "C" void kernel_launch(void* const* d_in, const int* in_sizes, int n_in,
                              void* d_out, int out_size, void* d_ws, size_t ws_size,
                              hipStream_t stream) {
  const float* x = (const float*)d_in[0];
  const float* s = (const float*)d_in[1];
  char* ws = (char*)d_ws;
  float* meanA = (float*)(ws + 0);
  float* meanB = (float*)(ws + 4096);
  float* invbn = (float*)(ws + 8192);
  float* rawNA = (float*)(ws + 73728);
  float* rawNB = (float*)(ws + 139264);
  float* dotbuf = (float*)(ws + 204800);
  int* best = (int*)(ws + 270336);
  __hip_bfloat16* Abf = (__hip_bfloat16*)(ws + 524288);
  __hip_bfloat16* Bbf = (__hip_bfloat16*)(ws + 524288 + 25165824);
  float* out = (float*)d_out;

  hipMemsetAsync(dotbuf, 0, HW * sizeof(float), stream);
  hipMemsetAsync(out, 0, sizeof(float), stream);
  k_means<<<2 * C_DIM, 256, 0, stream>>>(x, s, meanA, meanB);
  k_prep<<<HW / 64, 256, 0, stream>>>(x, s, meanA, meanB, Abf, Bbf, invbn, rawNA, rawNB);
  k_scaleb<<<(HW * CPR) / 256, 256, 0, stream>>>(Bbf, invbn);
  k_gemm_argmax<<<HW / 64, 256, 0, stream>>>(Abf, Bbf, best);
  k_loss1<<<256, 256, 0, stream>>>(x, s, best, dotbuf);
  k_loss2<<<HW / 256, 256, 0, stream>>>(dotbuf, best, rawNA, rawNB, out);
}

// Round 4
// 920.463 us; speedup vs baseline: 1.3407x; 1.0744x over previous
//
#include <hip/hip_runtime.h>
#include <hip/hip_bf16.h>
#include <stdint.h>

#define C_DIM 768
#define HW 16384
#define EPSF 1e-8f

typedef __attribute__((ext_vector_type(4))) int i32x4;

// ---------------- Kernel A: per-channel means over spatial dim ----------------
__global__ __launch_bounds__(256) void k_means(const float* __restrict__ x,
                                               const float* __restrict__ s,
                                               float* __restrict__ meanA,
                                               float* __restrict__ meanB) {
  int ch = blockIdx.x;
  const float* src = (ch < C_DIM) ? (x + (size_t)ch * HW) : (s + (size_t)(ch - C_DIM) * HW);
  int t = threadIdx.x;
  float acc = 0.f;
  for (int i = t; i < HW; i += 256) acc += src[i];
  __shared__ float red[256];
  red[t] = acc;
  __syncthreads();
  for (int o = 128; o > 0; o >>= 1) {
    if (t < o) red[t] += red[t + o];
    __syncthreads();
  }
  if (t == 0) {
    float m = red[0] * (1.0f / HW);
    if (ch < C_DIM) meanA[ch] = m; else meanB[ch - C_DIM] = m;
  }
}

// ---------------- Kernel S: per-position stats ----------------
// For each spatial position p: maxabs of centered a / centered b (quant scales),
// raw sumsq of a and b (final-loss norms), centered sumsq of b (invbn).
__global__ __launch_bounds__(256) void k_stats(const float* __restrict__ x,
                                               const float* __restrict__ s,
                                               const float* __restrict__ meanA,
                                               const float* __restrict__ meanB,
                                               float* __restrict__ qsa,
                                               float* __restrict__ qsb,
                                               float* __restrict__ eff,
                                               float* __restrict__ rawNA,
                                               float* __restrict__ rawNB) {
  __shared__ float lma[C_DIM], lmb[C_DIM];
  __shared__ float red[5 * 256];
  int t = threadIdx.x;
  int p0 = blockIdx.x * 64;
  for (int c = t; c < C_DIM; c += 256) { lma[c] = meanA[c]; lmb[c] = meanB[c]; }
  __syncthreads();
  int pl = t & 63, cl = t >> 6;
  int p = p0 + pl;
  float maxa = 0.f, ssaR = 0.f, maxb = 0.f, ssbC = 0.f, ssbR = 0.f;
  for (int c = cl; c < C_DIM; c += 4) {
    float av = x[(size_t)c * HW + p];
    float bv = s[(size_t)c * HW + p];
    float ac = av - lma[c];
    float bc = bv - lmb[c];
    maxa = fmaxf(maxa, fabsf(ac));
    maxb = fmaxf(maxb, fabsf(bc));
    ssaR += av * av;
    ssbC += bc * bc;
    ssbR += bv * bv;
  }
  red[t] = maxa; red[256 + t] = ssaR; red[512 + t] = maxb;
  red[768 + t] = ssbC; red[1024 + t] = ssbR;
  __syncthreads();
  if (t < 64) {
    float ma = fmaxf(fmaxf(red[t], red[t + 64]), fmaxf(red[t + 128], red[t + 192]));
    float sa = red[256 + t] + red[256 + t + 64] + red[256 + t + 128] + red[256 + t + 192];
    float mb = fmaxf(fmaxf(red[512 + t], red[512 + t + 64]), fmaxf(red[512 + t + 128], red[512 + t + 192]));
    float sc = red[768 + t] + red[768 + t + 64] + red[768 + t + 128] + red[768 + t + 192];
    float sb = red[1024 + t] + red[1024 + t + 64] + red[1024 + t + 128] + red[1024 + t + 192];
    ma = fmaxf(ma, 1e-20f);
    mb = fmaxf(mb, 1e-20f);
    float invbn = 1.0f / (sqrtf(sc + EPSF) + EPSF);
    qsa[p0 + t] = 127.0f / ma;
    qsb[p0 + t] = 127.0f / mb;
    eff[p0 + t] = (mb * (1.0f / 127.0f)) * invbn;
    rawNA[p0 + t] = sqrtf(sa);
    rawNB[p0 + t] = sqrtf(sb);
  }
}

// ---------------- Kernel Q: transpose + int8 quantize + MFMA-native pack -------
// qa[p][c] int8 row-major (768 B rows). Bp packed so that for col-group g (16 js)
// and kstep s (64 ks), the 64 lanes' 16-byte fragments are one contiguous 1024 B
// block: Bp[(g*12+s)*1024 + lane*16 + e], lane=(j&15)|(quad<<4), k=s*64+quad*16+e.
// A-frag loads use the identical (quad,byte)->k map, so any HW-internal k order
// cancels in the dot product.
__global__ __launch_bounds__(256) void k_quant(const float* __restrict__ x,
                                               const float* __restrict__ s,
                                               const float* __restrict__ meanA,
                                               const float* __restrict__ meanB,
                                               const float* __restrict__ qsa,
                                               const float* __restrict__ qsb,
                                               signed char* __restrict__ qa,
                                               signed char* __restrict__ Bp) {
  __shared__ float la[64 * 33];
  __shared__ float lb[64 * 33];
  __shared__ float lma[C_DIM], lmb[C_DIM];
  int t = threadIdx.x;
  int j0 = blockIdx.x * 64;
  for (int c = t; c < C_DIM; c += 256) { lma[c] = meanA[c]; lmb[c] = meanB[c]; }

  int wj = t >> 2;             // 0..63 position within block
  int wk = (t & 3) * 8;        // k offset within 32-chunk
  int p = j0 + wj;
  float sa = qsa[p];
  float sb = qsb[p];
  int g = p >> 4;
  int laneB = p & 15;

  for (int c0 = 0; c0 < C_DIM; c0 += 32) {
    __syncthreads();
#pragma unroll
    for (int sIt = 0; sIt < 8; ++sIt) {
      int idx = t + sIt * 256;
      int r = idx >> 6, cc = idx & 63;
      la[cc * 33 + r] = x[(size_t)(c0 + r) * HW + j0 + cc];
      lb[cc * 33 + r] = s[(size_t)(c0 + r) * HW + j0 + cc];
    }
    __syncthreads();
    unsigned long long pkA = 0, pkB = 0;
#pragma unroll
    for (int u = 0; u < 8; ++u) {
      int c = c0 + wk + u;
      float av = (la[wj * 33 + wk + u] - lma[c]) * sa;
      float bv = (lb[wj * 33 + wk + u] - lmb[c]) * sb;
      int qA = (int)rintf(fminf(fmaxf(av, -127.f), 127.f));
      int qB = (int)rintf(fminf(fmaxf(bv, -127.f), 127.f));
      pkA |= ((unsigned long long)(unsigned char)(signed char)qA) << (8 * u);
      pkB |= ((unsigned long long)(unsigned char)(signed char)qB) << (8 * u);
    }
    *(unsigned long long*)(qa + (size_t)p * C_DIM + c0 + wk) = pkA;
    int k0 = c0 + wk;
    int sblk = k0 >> 6;
    int quad = (k0 & 63) >> 4;
    int e0 = k0 & 15;
    *(unsigned long long*)(Bp + (size_t)(g * 12 + sblk) * 1024 + (laneB | (quad << 4)) * 16 + e0) = pkB;
  }
}

// ---------------- Kernel G: LDS-free i8 MFMA GEMM + fused argmax ----------------
// 256 blocks = 64 row-groups (256 rows) x 4 B-quarters (4096 cols).
// Wave owns 64 rows = 4 A-tiles held in registers (192 VGPR). B streamed
// direct-to-VGPR (double-buffered), 4 MFMAs per fragment. Raw s_barrier per
// group keeps the 4 waves lockstep so L1 serves waves 2-4.
__global__ __launch_bounds__(256, 1) void k_gemm_argmax(
    const signed char* __restrict__ qa,
    const signed char* __restrict__ Bp,
    const float* __restrict__ eff,
    unsigned long long* __restrict__ best) {
  int t = threadIdx.x;
  int lane = t & 63, w = t >> 6;
  int m = lane & 15, q = lane >> 4;
  int rg = blockIdx.x & 63;
  int bq = blockIdx.x >> 6;
  int i0 = rg * 256;
  int g0 = bq * 256, g1 = g0 + 256;

  const i32x4* qaV = (const i32x4*)qa;     // row = 48 chunks of 16 B
  const i32x4* BpV = (const i32x4*)Bp;

  // A fragments: 4 tiles x 12 ksteps, lane m = row, chunk s*4+q within row
  i32x4 a_res[4][12];
#pragma unroll
  for (int tm = 0; tm < 4; ++tm) {
    int row = i0 + w * 64 + tm * 16 + m;
#pragma unroll
    for (int s = 0; s < 12; ++s)
      a_res[tm][s] = qaV[(size_t)row * 48 + s * 4 + q];
  }

  float bestv[4][4];
  int bestj[4][4];
#pragma unroll
  for (int tm = 0; tm < 4; ++tm)
#pragma unroll
    for (int r = 0; r < 4; ++r) { bestv[tm][r] = -3.0e38f; bestj[tm][r] = 0x7FFFFFFF; }

  i32x4 fA[12], fB[12];
#pragma unroll
  for (int s = 0; s < 12; ++s) fA[s] = BpV[(size_t)(g0 * 12 + s) * 64 + lane];

#define GBODY(FCUR, FNXT, GG, GN)                                               \
  {                                                                             \
    __builtin_amdgcn_s_barrier();                                               \
    int _gn = (GN);                                                             \
    _Pragma("unroll")                                                           \
    for (int s = 0; s < 12; ++s) FNXT[s] = BpV[(size_t)(_gn * 12 + s) * 64 + lane]; \
    float ev = eff[((GG) << 4) + m];                                            \
    i32x4 acc0 = {0,0,0,0}, acc1 = {0,0,0,0}, acc2 = {0,0,0,0}, acc3 = {0,0,0,0}; \
    _Pragma("unroll")                                                           \
    for (int s = 0; s < 12; ++s) {                                              \
      acc0 = __builtin_amdgcn_mfma_i32_16x16x64_i8(a_res[0][s], FCUR[s], acc0, 0, 0, 0); \
      acc1 = __builtin_amdgcn_mfma_i32_16x16x64_i8(a_res[1][s], FCUR[s], acc1, 0, 0, 0); \
      acc2 = __builtin_amdgcn_mfma_i32_16x16x64_i8(a_res[2][s], FCUR[s], acc2, 0, 0, 0); \
      acc3 = __builtin_amdgcn_mfma_i32_16x16x64_i8(a_res[3][s], FCUR[s], acc3, 0, 0, 0); \
    }                                                                           \
    int jj = ((GG) << 4) + m;                                                   \
    _Pragma("unroll")                                                           \
    for (int r = 0; r < 4; ++r) {                                               \
      float v0 = (float)acc0[r] * ev;                                           \
      float v1 = (float)acc1[r] * ev;                                           \
      float v2 = (float)acc2[r] * ev;                                           \
      float v3 = (float)acc3[r] * ev;                                           \
      if (v0 > bestv[0][r]) { bestv[0][r] = v0; bestj[0][r] = jj; }             \
      if (v1 > bestv[1][r]) { bestv[1][r] = v1; bestj[1][r] = jj; }             \
      if (v2 > bestv[2][r]) { bestv[2][r] = v2; bestj[2][r] = jj; }             \
      if (v3 > bestv[3][r]) { bestv[3][r] = v3; bestj[3][r] = jj; }             \
    }                                                                           \
  }

  for (int g = g0; g < g1; g += 2) {
    int gn1 = g + 1;                       // always < g1 (256 even)
    int gn2 = (g + 2 < g1) ? (g + 2) : (g1 - 1);
    GBODY(fA, fB, g, gn1)
    GBODY(fB, fA, gn1, gn2)
  }
#undef GBODY

  // reduce over 16 lanes (columns), then merge quarters via packed atomicMax
#pragma unroll
  for (int tm = 0; tm < 4; ++tm) {
#pragma unroll
    for (int r = 0; r < 4; ++r) {
      float bv = bestv[tm][r];
      int bj = bestj[tm][r];
#pragma unroll
      for (int off = 1; off < 16; off <<= 1) {
        float ov = __shfl_xor(bv, off, 64);
        int oj = __shfl_xor(bj, off, 64);
        if (ov > bv || (ov == bv && oj < bj)) { bv = ov; bj = oj; }
      }
      if (m == 0) {
        int i = i0 + w * 64 + tm * 16 + q * 4 + r;
        unsigned key = __float_as_uint(bv);
        key = (key & 0x80000000u) ? ~key : (key | 0x80000000u);
        unsigned long long packed =
            ((unsigned long long)key << 32) | (unsigned long long)(0xFFFFFFFFu - (unsigned)bj);
        atomicMax(&best[i], packed);
      }
    }
  }
}

// ---------------- Kernel D1: partial dots (c split 4 ways) ----------------
__global__ __launch_bounds__(256) void k_loss1(const float* __restrict__ x,
                                               const float* __restrict__ s,
                                               const unsigned long long* __restrict__ best,
                                               float* __restrict__ dotbuf) {
  int bid = blockIdx.x;
  int ib = bid & 63, seg = bid >> 6;
  int i = ib * 256 + threadIdx.x;
  int j = (int)(0xFFFFFFFFu - (unsigned)(best[i] & 0xFFFFFFFFull));
  int c0 = seg * 192;
  float dot = 0.f;
  for (int c = c0; c < c0 + 192; ++c)
    dot += x[(size_t)c * HW + i] * s[(size_t)c * HW + j];
  atomicAdd(&dotbuf[i], dot);
}

// ---------------- Kernel D2: final cosine loss ----------------
__global__ __launch_bounds__(256) void k_loss2(const float* __restrict__ dotbuf,
                                               const unsigned long long* __restrict__ best,
                                               const float* __restrict__ rawNA,
                                               const float* __restrict__ rawNB,
                                               float* __restrict__ out) {
  int i = blockIdx.x * 256 + threadIdx.x;
  int j = (int)(0xFFFFFFFFu - (unsigned)(best[i] & 0xFFFFFFFFull));
  float cs = dotbuf[i] / ((rawNA[i] + EPSF) * (rawNB[j] + EPSF));
  float term = (1.0f - cs) * (1.0f / HW);
  __shared__ float red[256];
  int t = threadIdx.x;
  red[t] = term;
  __syncthreads();
  for (int o = 128; o > 0; o >>= 1) {
    if (t < o) red[t] += red[t + o];
    __syncthreads();
  }
  if (t == 0) atomicAdd(out, red[0]);
}

// ---------------- Launch ----------------
extern "C" void kernel_launch(void* const* d_in, const int* in_sizes, int n_in,
                              void* d_out, int out_size, void* d_ws, size_t ws_size,
                              hipStream_t stream) {
  const float* x = (const float*)d_in[0];
  const float* s = (const float*)d_in[1];
  char* ws = (char*)d_ws;
  float* meanA = (float*)(ws + 0);
  float* meanB = (float*)(ws + 4096);
  float* rawNA = (float*)(ws + 8192);
  float* rawNB = (float*)(ws + 73728);
  float* eff   = (float*)(ws + 139264);
  float* qsa   = (float*)(ws + 204800);
  float* qsb   = (float*)(ws + 270336);
  float* dotbuf = (float*)(ws + 335872);
  unsigned long long* best = (unsigned long long*)(ws + 401408);
  signed char* qa = (signed char*)(ws + 532480);
  signed char* Bp = (signed char*)(ws + 532480 + 12582912);
  float* out = (float*)d_out;

  hipMemsetAsync(best, 0, HW * sizeof(unsigned long long), stream);
  hipMemsetAsync(dotbuf, 0, HW * sizeof(float), stream);
  hipMemsetAsync(out, 0, sizeof(float), stream);
  k_means<<<2 * C_DIM, 256, 0, stream>>>(x, s, meanA, meanB);
  k_stats<<<HW / 64, 256, 0, stream>>>(x, s, meanA, meanB, qsa, qsb, eff, rawNA, rawNB);
  k_quant<<<HW / 64, 256, 0, stream>>>(x, s, meanA, meanB, qsa, qsb, qa, Bp);
  k_gemm_argmax<<<256, 256, 0, stream>>>(qa, Bp, eff, best);
  k_loss1<<<256, 256, 0, stream>>>(x, s, best, dotbuf);
  k_loss2<<<HW / 256, 256, 0, stream>>>(dotbuf, best, rawNA, rawNB, out);
}